// Round 1
// baseline (216.259 us; speedup 1.0000x reference)
//
#include <hip/hip_runtime.h>

#define CH 64
#define ROWS_PER_BLOCK 8
#define BLOCK (ROWS_PER_BLOCK * 64)

// Kernel A: row_ptr[r] = first edge index e with edge_row[e] >= r  (r in [0, N])
__global__ __launch_bounds__(256) void build_row_ptr(
    const int* __restrict__ erow, int* __restrict__ rp, int N, int E)
{
    int r = blockIdx.x * 256 + threadIdx.x;
    if (r > N) return;
    int lo = 0, len = E;
    while (len > 0) {
        int half = len >> 1;
        int probe = lo + half;
        int v = erow[probe];
        if (v < r) { lo = probe + 1; len -= half + 1; }
        else { len = half; }
    }
    rp[r] = lo;
}

// Kernel B: fused spmm (register accumulation, one wave per row, lane=channel)
// + per-row matvec with w staged in LDS.
__global__ __launch_bounds__(BLOCK, 6) void sdconv_fused(
    const float* __restrict__ Xr, const float* __restrict__ Xi,
    const float* __restrict__ Lr, const float* __restrict__ Li,
    const float* __restrict__ W, const float* __restrict__ bias,
    const int* __restrict__ ecol, const int* __restrict__ rp,
    float* __restrict__ outR, float* __restrict__ outI,
    int N, int E)
{
    __shared__ float w_lds[2 * CH * CH];                       // 32 KB
    __shared__ __align__(16) float scratch[ROWS_PER_BLOCK][4 * CH]; // 8 KB

    const int t = threadIdx.x;
    for (int i = t; i < 2 * CH * CH; i += BLOCK) w_lds[i] = W[i];
    __syncthreads();

    const int wave = t >> 6;
    const int lane = t & 63;
    const int row = blockIdx.x * ROWS_PER_BLOCK + wave;
    if (row >= N) return;  // no barriers after this point

    // wave-uniform edge range (force SGPR so edge/val loads become s_loads)
    int start = __builtin_amdgcn_readfirstlane(rp[row]);
    int end   = __builtin_amdgcn_readfirstlane(rp[row + 1]);

    const float* __restrict__ Lr1 = Lr + E;
    const float* __restrict__ Li1 = Li + E;

    // A_k = sum lr_k*Xr[col] - li_k*Xi[col];  B_k = sum li_k*Xr[col] + lr_k*Xi[col]
    float a0 = 0.f, b0 = 0.f, a1 = 0.f, b1 = 0.f;
    int e = start;
    for (; e + 1 < end; e += 2) {
        int c0 = ecol[e], c1 = ecol[e + 1];
        float xr0 = Xr[c0 * CH + lane];
        float xi0 = Xi[c0 * CH + lane];
        float xr1 = Xr[c1 * CH + lane];
        float xi1 = Xi[c1 * CH + lane];
        float p0r = Lr[e],     p0i = Li[e],     q0r = Lr1[e],     q0i = Li1[e];
        float p1r = Lr[e + 1], p1i = Li[e + 1], q1r = Lr1[e + 1], q1i = Li1[e + 1];
        a0 += p0r * xr0 - p0i * xi0;
        b0 += p0i * xr0 + p0r * xi0;
        a1 += q0r * xr0 - q0i * xi0;
        b1 += q0i * xr0 + q0r * xi0;
        a0 += p1r * xr1 - p1i * xi1;
        b0 += p1i * xr1 + p1r * xi1;
        a1 += q1r * xr1 - q1i * xi1;
        b1 += q1i * xr1 + q1r * xi1;
    }
    if (e < end) {
        int c0 = ecol[e];
        float xr0 = Xr[c0 * CH + lane];
        float xi0 = Xi[c0 * CH + lane];
        float p0r = Lr[e], p0i = Li[e], q0r = Lr1[e], q0i = Li1[e];
        a0 += p0r * xr0 - p0i * xi0;
        b0 += p0i * xr0 + p0r * xi0;
        a1 += q0r * xr0 - q0i * xi0;
        b1 += q0i * xr0 + q0r * xi0;
    }

    // stage per-wave accumulator vectors for the transpose (lane=channel -> need all channels)
    float* sl = scratch[wave];
    sl[0 * CH + lane] = a0;
    sl[1 * CH + lane] = a1;
    sl[2 * CH + lane] = b0;
    sl[3 * CH + lane] = b1;
    __asm__ volatile("s_waitcnt lgkmcnt(0)" ::: "memory");  // wave-local LDS RAW fence

    // matvec: out[j] = bias[j] + sum_c A0[c] w0[c][j] + A1[c] w1[c][j]  (j = lane)
    float bv = bias[lane];
    float accR = bv, accI = bv;
    const float* w0 = w_lds;
    const float* w1 = w_lds + CH * CH;
    #pragma unroll
    for (int c4 = 0; c4 < CH / 4; ++c4) {
        float4 A0 = *(const float4*)&sl[0 * CH + c4 * 4];  // b128 broadcast reads
        float4 A1 = *(const float4*)&sl[1 * CH + c4 * 4];
        float4 B0 = *(const float4*)&sl[2 * CH + c4 * 4];
        float4 B1 = *(const float4*)&sl[3 * CH + c4 * 4];
        #pragma unroll
        for (int cc = 0; cc < 4; ++cc) {
            int c = c4 * 4 + cc;
            float w0v = w0[c * CH + lane];   // stride-1 across lanes: conflict-free
            float w1v = w1[c * CH + lane];
            float a0c = (&A0.x)[cc], a1c = (&A1.x)[cc];
            float b0c = (&B0.x)[cc], b1c = (&B1.x)[cc];
            accR += a0c * w0v + a1c * w1v;
            accI += b0c * w0v + b1c * w1v;
        }
    }
    outR[(size_t)row * CH + lane] = accR;
    outI[(size_t)row * CH + lane] = accI;
}

extern "C" void kernel_launch(void* const* d_in, const int* in_sizes, int n_in,
                              void* d_out, int out_size, void* d_ws, size_t ws_size,
                              hipStream_t stream)
{
    const float* Xr   = (const float*)d_in[0];
    const float* Xi   = (const float*)d_in[1];
    const float* Lr   = (const float*)d_in[2];
    const float* Li   = (const float*)d_in[3];
    const float* W    = (const float*)d_in[4];
    const float* bias = (const float*)d_in[5];
    const int*   erow = (const int*)d_in[6];
    const int*   ecol = (const int*)d_in[7];

    const int N = in_sizes[0] / CH;
    const int E = in_sizes[6];

    int* rp = (int*)d_ws;                 // (N+1) ints of scratch
    float* outR = (float*)d_out;
    float* outI = outR + (size_t)N * CH;

    int nb_rp = (N + 1 + 255) / 256;
    hipLaunchKernelGGL(build_row_ptr, dim3(nb_rp), dim3(256), 0, stream,
                       erow, rp, N, E);

    int nb = (N + ROWS_PER_BLOCK - 1) / ROWS_PER_BLOCK;
    hipLaunchKernelGGL(sdconv_fused, dim3(nb), dim3(BLOCK), 0, stream,
                       Xr, Xi, Lr, Li, W, bias, ecol, rp, outR, outI, N, E);
}